// Round 8
// baseline (291.807 us; speedup 1.0000x reference)
//
#include <hip/hip_runtime.h>
#include <hip/hip_bf16.h>
#include <math.h>

// Problem constants
#define B_  2
#define T_  2048
#define C_  1536
#define H_  12
#define KV_ 4
#define D_  128
#define M_  (B_*T_)   // 4096 rows
#define REP_ (H_/KV_) // 3
#define NQKV_ 2560    // fused q|k|v output width

typedef __bf16 bf16x8 __attribute__((ext_vector_type(8)));
typedef float  f32x4  __attribute__((ext_vector_type(4)));
typedef unsigned u32x4 __attribute__((ext_vector_type(4)));

union BCast { u32x4 u; bf16x8 b; ushort s[8]; };

__device__ inline bf16x8 ldb8(const ushort* p) {
    BCast c; c.u = *reinterpret_cast<const u32x4*>(p); return c.b;
}

__device__ inline ushort f2bf(float f) {
    union { float f; unsigned u; } v; v.f = f;
    unsigned u = v.u;
    return (ushort)((u + 0x7FFF + ((u >> 16) & 1)) >> 16);
}

__device__ inline float bf2f(ushort u) {
    union { unsigned u; float f; } v; v.u = (unsigned)u << 16;
    return v.f;
}

// async global->LDS, 16 bytes per lane; lds base must be wave-uniform
__device__ inline void async_copy16(const ushort* g, ushort* l) {
    __builtin_amdgcn_global_load_lds(
        (const __attribute__((address_space(1))) unsigned*)g,
        (__attribute__((address_space(3))) unsigned*)l, 16, 0, 0);
}

// d-permutation for rope-pair locality: swap middle two 32-blocks of each head.
// Applied to Wq AND Wk rows => QK^T unchanged; pairs (i,i+64) -> (p, p+32).
__device__ __host__ inline int dperm(int d) {
    return (d < 32) ? d : (d < 64 ? d + 32 : (d < 96 ? d - 32 : d));
}

// ---------------------------------------------------------------------------
// bf16 MFMA GEMM (m97 structure): C[M,N] = A[M,K] * B[N,K]^T  (proj path)
// ---------------------------------------------------------------------------
template<bool BF16OUT>
__global__ __launch_bounds__(256) void gemm_bf16_bt(const ushort* __restrict__ A,
                                                    const ushort* __restrict__ Bm,
                                                    void* __restrict__ Cp,
                                                    int M, int N, int K) {
    __shared__ ushort As[128 * 32];
    __shared__ ushort Bs[128 * 32];
    const int tid  = threadIdx.x;
    const int wave = tid >> 6, lane = tid & 63;
    const int m16 = lane & 15, quad = lane >> 4;
    const int bm = blockIdx.y * 128, bn = blockIdx.x * 128;
    const int wm = (wave >> 1) * 64, wn = (wave & 1) * 64;

    const int lrow = lane >> 2;
    const int lcol = (lane & 3) * 8;
    const ushort* Ag = A  + (size_t)(bm + wave * 16 + lrow) * K + lcol;
    const ushort* Bg = Bm + (size_t)(bn + wave * 16 + lrow) * K + lcol;
    ushort* AsW0 = As + wave * 512;
    ushort* AsW1 = As + 2048 + wave * 512;
    ushort* BsW0 = Bs + wave * 512;
    ushort* BsW1 = Bs + 2048 + wave * 512;
    const size_t rowskip = (size_t)64 * K;

    f32x4 acc[4][4];
    #pragma unroll
    for (int i = 0; i < 4; i++)
        #pragma unroll
        for (int j = 0; j < 4; j++) acc[i][j] = (f32x4){0.f, 0.f, 0.f, 0.f};

    for (int k0 = 0; k0 < K; k0 += 32) {
        async_copy16(Ag + k0,           AsW0);
        async_copy16(Ag + k0 + rowskip, AsW1);
        async_copy16(Bg + k0,           BsW0);
        async_copy16(Bg + k0 + rowskip, BsW1);
        __syncthreads();

        bf16x8 af[4], bfr[4];
        #pragma unroll
        for (int i = 0; i < 4; i++)
            af[i] = ldb8(As + (wm + i * 16 + m16) * 32 + quad * 8);
        #pragma unroll
        for (int j = 0; j < 4; j++)
            bfr[j] = ldb8(Bs + (wn + j * 16 + m16) * 32 + quad * 8);
        #pragma unroll
        for (int i = 0; i < 4; i++)
            #pragma unroll
            for (int j = 0; j < 4; j++)
                acc[i][j] = __builtin_amdgcn_mfma_f32_16x16x32_bf16(af[i], bfr[j], acc[i][j], 0, 0, 0);
        __syncthreads();
    }

    #pragma unroll
    for (int i = 0; i < 4; i++) {
        #pragma unroll
        for (int reg = 0; reg < 4; reg++) {
            const int row = bm + wm + i * 16 + quad * 4 + reg;
            if constexpr (BF16OUT) {
                ushort* C = (ushort*)Cp;
                #pragma unroll
                for (int j = 0; j < 4; j++)
                    C[(size_t)row * N + bn + wn + j * 16 + m16] = f2bf(acc[i][j][reg]);
            } else {
                float* C = (float*)Cp;
                #pragma unroll
                for (int j = 0; j < 4; j++)
                    C[(size_t)row * N + bn + wn + j * 16 + m16] = acc[i][j][reg];
            }
        }
    }
}

// ---------------------------------------------------------------------------
// Fused QKV GEMM, plain bf16 epilogue routed by bn:
//   bn<1536   : q head h=bn/128 -> Qp [(b*H+h)*T+t][128]  (raw, permuted d)
//   1536..2047: k group          -> Kp [(b*KV+g)*T+t][128] (raw, permuted d)
//   >=2048    : v -> vbuf[row][512] (original d order)
// ---------------------------------------------------------------------------
#define KQ_ 1536
__global__ __launch_bounds__(256) void gemm_qkv(const ushort* __restrict__ A,
                                                const ushort* __restrict__ Bm,
                                                ushort* __restrict__ Qp,
                                                ushort* __restrict__ Kp,
                                                ushort* __restrict__ vbuf) {
    __shared__ ushort As[128 * 32];
    __shared__ ushort Bs[128 * 32];
    const int tid  = threadIdx.x;
    const int wave = tid >> 6, lane = tid & 63;
    const int m16 = lane & 15, quad = lane >> 4;
    const int bm = blockIdx.y * 128, bn = blockIdx.x * 128;
    const int wm = (wave >> 1) * 64, wn = (wave & 1) * 64;

    const int lrow = lane >> 2;
    const int lcol = (lane & 3) * 8;
    const ushort* Ag = A  + (size_t)(bm + wave * 16 + lrow) * KQ_ + lcol;
    const ushort* Bg = Bm + (size_t)(bn + wave * 16 + lrow) * KQ_ + lcol;
    ushort* AsW0 = As + wave * 512;
    ushort* AsW1 = As + 2048 + wave * 512;
    ushort* BsW0 = Bs + wave * 512;
    ushort* BsW1 = Bs + 2048 + wave * 512;
    const size_t rowskip = (size_t)64 * KQ_;

    f32x4 acc[4][4];
    #pragma unroll
    for (int i = 0; i < 4; i++)
        #pragma unroll
        for (int j = 0; j < 4; j++) acc[i][j] = (f32x4){0.f, 0.f, 0.f, 0.f};

    for (int k0 = 0; k0 < KQ_; k0 += 32) {
        async_copy16(Ag + k0,           AsW0);
        async_copy16(Ag + k0 + rowskip, AsW1);
        async_copy16(Bg + k0,           BsW0);
        async_copy16(Bg + k0 + rowskip, BsW1);
        __syncthreads();

        bf16x8 af[4], bfr[4];
        #pragma unroll
        for (int i = 0; i < 4; i++)
            af[i] = ldb8(As + (wm + i * 16 + m16) * 32 + quad * 8);
        #pragma unroll
        for (int j = 0; j < 4; j++)
            bfr[j] = ldb8(Bs + (wn + j * 16 + m16) * 32 + quad * 8);
        #pragma unroll
        for (int i = 0; i < 4; i++)
            #pragma unroll
            for (int j = 0; j < 4; j++)
                acc[i][j] = __builtin_amdgcn_mfma_f32_16x16x32_bf16(af[i], bfr[j], acc[i][j], 0, 0, 0);
        __syncthreads();
    }

    if (bn < 2048) {
        const bool isq = (bn < 1536);
        const int hh = isq ? (bn >> 7) : ((bn - 1536) >> 7);
        const int nh = isq ? H_ : KV_;
        ushort* outp = isq ? Qp : Kp;
        #pragma unroll
        for (int i = 0; i < 4; i++) {
            #pragma unroll
            for (int reg = 0; reg < 4; reg++) {
                const int row = bm + wm + i * 16 + quad * 4 + reg;
                const int b = row >> 11, t = row & (T_ - 1);
                ushort* orow = outp + ((size_t)(b * nh + hh) * T_ + t) * D_ + wn + m16;
                #pragma unroll
                for (int j = 0; j < 4; j++)
                    orow[j * 16] = f2bf(acc[i][j][reg]);
            }
        }
    } else {
        const int cb = bn - 2048 + wn;
        #pragma unroll
        for (int i = 0; i < 4; i++) {
            #pragma unroll
            for (int reg = 0; reg < 4; reg++) {
                const int row = bm + wm + i * 16 + quad * 4 + reg;
                ushort* vr = vbuf + (size_t)row * 512 + cb + m16;
                #pragma unroll
                for (int j = 0; j < 4; j++)
                    vr[j * 16] = f2bf(acc[i][j][reg]);
            }
        }
    }
}

// ---------------------------------------------------------------------------
// Fused segmented fp32->bf16 cast of x, Wq, Wk, Wv, Wproj (one launch).
// Wq/Wk rows are written in dperm order (rope-pair locality).
// ---------------------------------------------------------------------------
#define SEG0 1572864   // x      : 4096*1536/4
#define SEG1 2162688   // + Wq   : 1536*1536/4
#define SEG2 2359296   // + Wk   : 512*1536/4
#define SEG3 2555904   // + Wv   : 512*1536/4
#define SEG4 3145728   // + Wproj: 1536*1536/4
#define ROW4 384       // float4s per 1536-col row
__global__ __launch_bounds__(256) void cast_all(const float* __restrict__ x,
                                                const float* __restrict__ Wq,
                                                const float* __restrict__ Wk,
                                                const float* __restrict__ Wv,
                                                const float* __restrict__ Wp,
                                                ushort* __restrict__ xb,
                                                ushort* __restrict__ Wqkvb,
                                                ushort* __restrict__ Wpb) {
    const int i = blockIdx.x * 256 + threadIdx.x;
    float4 v; size_t dst4; ushort* dstp;
    if (i < SEG0) {
        v = ((const float4*)x)[i]; dstp = xb; dst4 = i;
    } else if (i < SEG1) {
        const int j = i - SEG0;
        const int r = j / ROW4, c4 = j - r * ROW4;
        const int d = r & 127, hh = r >> 7;
        v = ((const float4*)Wq)[j]; dstp = Wqkvb;
        dst4 = (size_t)(hh * 128 + dperm(d)) * ROW4 + c4;
    } else if (i < SEG2) {
        const int j = i - SEG1;
        const int r = j / ROW4, c4 = j - r * ROW4;
        const int d = r & 127, g = r >> 7;
        v = ((const float4*)Wk)[j]; dstp = Wqkvb;
        dst4 = (size_t)(1536 + g * 128 + dperm(d)) * ROW4 + c4;
    } else if (i < SEG3) {
        const int j = i - SEG2;
        v = ((const float4*)Wv)[j]; dstp = Wqkvb;
        dst4 = (size_t)2048 * ROW4 + j;
    } else {
        const int j = i - SEG3;
        v = ((const float4*)Wp)[j]; dstp = Wpb; dst4 = j;
    }
    ((ushort4*)dstp)[dst4] = make_ushort4(f2bf(v.x), f2bf(v.y), f2bf(v.z), f2bf(v.w));
}

// ---------------------------------------------------------------------------
// In-place rope + rmsnorm on Kp (permuted-d layout, pairs at (p, p+32)).
// 4 rows per 256-thread block; lane L: p = L<32 ? L : L+32; cos idx = L.
// ---------------------------------------------------------------------------
__global__ __launch_bounds__(256) void rope_rms_k(ushort* __restrict__ Kp,
                                                  const float* __restrict__ cosb,
                                                  const float* __restrict__ sinb) {
    const int row = blockIdx.x * 4 + (threadIdx.x >> 6);  // (b*KV+g)*T + t
    const int t = row & (T_ - 1);
    ushort* p = Kp + (size_t)row * D_;
    const int L = threadIdx.x & 63;
    const int pp = (L < 32) ? L : L + 32;
    const float c = cosb[t * 64 + L], s = sinb[t * 64 + L];
    const float x1 = bf2f(p[pp]), x2 = bf2f(p[pp + 32]);
    float ssq = x1 * x1 + x2 * x2;
    #pragma unroll
    for (int off = 32; off > 0; off >>= 1) ssq += __shfl_xor(ssq, off);
    const float scale = rsqrtf(ssq * (1.0f / 128.0f) + 1.1920928955078125e-07f);
    p[pp]      = f2bf((x1 * c + x2 * s) * scale);
    p[pp + 32] = f2bf((x2 * c - x1 * s) * scale);
}

// ---------------------------------------------------------------------------
// Fused ve-gate + transpose: Vt[b][g][d][s] = vbuf[bt][g*128+d] + gate*ve
// ---------------------------------------------------------------------------
__global__ __launch_bounds__(256) void gate_vt(const ushort* __restrict__ vbuf,
                                               const float* __restrict__ x,
                                               const float* __restrict__ ve,
                                               const float* __restrict__ Wg,
                                               ushort* __restrict__ Vt) {
    const int t0 = blockIdx.x * 64, g = blockIdx.y, b = blockIdx.z;
    __shared__ float gateS[64];
    __shared__ ushort tile[128][66];   // [d][t], padded
    const int tid = threadIdx.x;
    if (tid < 64) {
        const float* xr = x + (size_t)(b * T_ + t0 + tid) * C_;
        float acc = 0.f;
        #pragma unroll
        for (int c = 0; c < 12; c++) acc += xr[c] * Wg[g * 12 + c];
        gateS[tid] = 3.0f / (1.0f + __expf(-acc));
    }
    __syncthreads();
    #pragma unroll
    for (int i = 0; i < 32; i++) {
        int idx = i * 256 + tid;       // 0..8191
        int r = idx >> 7;              // t within tile
        int d = idx & 127;
        size_t offv = (size_t)(b * T_ + t0 + r) * 512 + g * D_ + d;
        tile[d][r] = f2bf(bf2f(vbuf[offv]) + gateS[r] * ve[offv]);
    }
    __syncthreads();
    ushort* ob = Vt + ((size_t)(b * KV_ + g) * D_) * T_ + t0;
    #pragma unroll
    for (int i = 0; i < 32; i++) {
        int idx = i * 256 + tid;
        int d = idx >> 6;              // 0..127
        int c = idx & 63;
        ob[(size_t)d * T_ + c] = tile[d][c];
    }
}

// ---------------------------------------------------------------------------
// Flash attention v5: block = (b, h, 128 queries), 4 waves x 32 queries.
// Q rope+rms applied in-register at load (Qp raw, permuted d).
// Static-max softmax + ones-MFMA l; K/V staged via global_load_lds.
// K/V fragments reused across 2 m-tiles per wave (2x arithmetic intensity).
// ---------------------------------------------------------------------------
__global__ __launch_bounds__(256, 2) void attn_mfma(const ushort* __restrict__ Qp,
                                                    const ushort* __restrict__ Kp,
                                                    const ushort* __restrict__ Vt,
                                                    ushort* __restrict__ Y,
                                                    const int* __restrict__ wptr,
                                                    const float* __restrict__ cosb,
                                                    const float* __restrict__ sinb) {
    const int t0 = blockIdx.x * 128;
    const int h  = blockIdx.y, b = blockIdx.z;
    const int g  = h / REP_;
    const int tid  = threadIdx.x;
    const int wave = tid >> 6, lane = tid & 63;
    const int m16 = lane & 15, quad = lane >> 4;

    __shared__ ushort Ks[4 * 32 * 32];   // 8 KB
    __shared__ ushort Vs[128 * 32];      // 8 KB
    __shared__ ushort Pl[4][32 * 40];    // 10 KB, per-wave P buffers (32 rows)

    const int w = *wptr;
    const bool windowed = (w >= 0 && w < T_);
    const unsigned wu = windowed ? (unsigned)w : 0x7FFFFFFFu;
    int s_lo = 0;
    if (windowed) { s_lo = t0 - w; if (s_lo < 0) s_lo = 0; }
    const int s_hi = t0 + 127;
    const int ss0 = s_lo & ~31;
    const int tw = t0 + wave * 32;       // this wave's first query row

    // ---- Q load (2 m-tiles) + in-register rope + rms ----
    bf16x8 qa[2][4];
    #pragma unroll
    for (int mt = 0; mt < 2; mt++) {
        const int t = tw + mt * 16 + m16;
        const ushort* qrow = Qp + ((size_t)(b * H_ + h) * T_ + t) * D_ + quad * 8;
        float qf[4][8];
        float ssq = 0.f;
        #pragma unroll
        for (int kc = 0; kc < 4; kc++) {
            BCast c; c.u = *reinterpret_cast<const u32x4*>(qrow + kc * 32);
            #pragma unroll
            for (int j = 0; j < 8; j++) {
                const float f = bf2f(c.s[j]);
                qf[kc][j] = f; ssq += f * f;
            }
        }
        ssq += __shfl_xor(ssq, 16);
        ssq += __shfl_xor(ssq, 32);
        const float scale = rsqrtf(ssq * (1.0f / 128.0f) + 1.1920928955078125e-07f)
                          * (1.2f * 1.2f * 0.08838834764831845f);
        const float* cb = cosb + t * 64 + quad * 8;
        const float* sb = sinb + t * 64 + quad * 8;
        BCast o0, o1, o2, o3;
        #pragma unroll
        for (int j = 0; j < 8; j++) {
            const float c0 = cb[j],      s0 = sb[j];       // pairs: chunks 0<->1
            const float c1 = cb[32 + j], s1 = sb[32 + j];  // pairs: chunks 2<->3
            o0.s[j] = f2bf((qf[0][j] * c0 + qf[1][j] * s0) * scale);
            o1.s[j] = f2bf((qf[1][j] * c0 - qf[0][j] * s0) * scale);
            o2.s[j] = f2bf((qf[2][j] * c1 + qf[3][j] * s1) * scale);
            o3.s[j] = f2bf((qf[3][j] * c1 - qf[2][j] * s1) * scale);
        }
        qa[mt][0] = o0.b; qa[mt][1] = o1.b; qa[mt][2] = o2.b; qa[mt][3] = o3.b;
    }

    const ushort* kbase = Kp + (size_t)(b * KV_ + g) * T_ * D_;
    const ushort* vbase = Vt + (size_t)(b * KV_ + g) * D_ * T_;

    // staging: wave handles chunks wave and wave+4 (of 8) for K and V
    const int c0 = wave, c1 = wave + 4;
    const ushort* kg0 = kbase + (size_t)((c0 & 1) * 16 + (lane >> 2)) * D_ + (c0 >> 1) * 32 + (lane & 3) * 8;
    const ushort* kg1 = kbase + (size_t)((c1 & 1) * 16 + (lane >> 2)) * D_ + (c1 >> 1) * 32 + (lane & 3) * 8;
    ushort* kl0 = Ks + c0 * 512;
    ushort* kl1 = Ks + c1 * 512;
    const ushort* vg0 = vbase + (size_t)(c0 * 16 + (lane >> 2)) * T_ + (lane & 3) * 8;
    const ushort* vg1 = vbase + (size_t)(c1 * 16 + (lane >> 2)) * T_ + (lane & 3) * 8;
    ushort* vl0 = Vs + c0 * 512;
    ushort* vl1 = Vs + c1 * 512;

    f32x4 o[2][8];
    f32x4 lacc[2];
    #pragma unroll
    for (int mt = 0; mt < 2; mt++) {
        lacc[mt] = (f32x4){0.f, 0.f, 0.f, 0.f};
        #pragma unroll
        for (int dt = 0; dt < 8; dt++) o[mt][dt] = (f32x4){0.f, 0.f, 0.f, 0.f};
    }
    BCast onesc; onesc.u = (u32x4){0x3F803F80u, 0x3F803F80u, 0x3F803F80u, 0x3F803F80u};
    const bf16x8 ones = onesc.b;
    ushort* pw = &Pl[wave][0];

    for (int ss = ss0; ss <= s_hi; ss += 32) {
        // ---- cooperative staging ----
        const size_t koff = (size_t)ss * D_;
        async_copy16(kg0 + koff, kl0);
        async_copy16(kg1 + koff, kl1);
        async_copy16(vg0 + ss,   vl0);
        async_copy16(vg1 + ss,   vl1);
        __syncthreads();   // tile ready (barrier drains vmcnt)

        // ---- S = Q K^T (32 q x 32 s); K frags shared across m-tiles ----
        f32x4 sc[2][2];
        #pragma unroll
        for (int mt = 0; mt < 2; mt++)
            #pragma unroll
            for (int hf = 0; hf < 2; hf++) sc[mt][hf] = (f32x4){0.f,0.f,0.f,0.f};
        #pragma unroll
        for (int kc = 0; kc < 4; kc++) {
            bf16x8 kf0 = ldb8(Ks + kc * 1024 + m16 * 32 + quad * 8);
            bf16x8 kf1 = ldb8(Ks + kc * 1024 + (16 + m16) * 32 + quad * 8);
            sc[0][0] = __builtin_amdgcn_mfma_f32_16x16x32_bf16(qa[0][kc], kf0, sc[0][0], 0, 0, 0);
            sc[0][1] = __builtin_amdgcn_mfma_f32_16x16x32_bf16(qa[0][kc], kf1, sc[0][1], 0, 0, 0);
            sc[1][0] = __builtin_amdgcn_mfma_f32_16x16x32_bf16(qa[1][kc], kf0, sc[1][0], 0, 0, 0);
            sc[1][1] = __builtin_amdgcn_mfma_f32_16x16x32_bf16(qa[1][kc], kf1, sc[1][1], 0, 0, 0);
        }

        // ---- mask + exp (static max) ----
        #pragma unroll
        for (int mt = 0; mt < 2; mt++) {
            #pragma unroll
            for (int hf = 0; hf < 2; hf++) {
                const int sA = ss + hf * 16 + m16;
                #pragma unroll
                for (int reg = 0; reg < 4; reg++) {
                    const int t = tw + mt * 16 + quad * 4 + reg;
                    const float p = ((unsigned)(t - sA) <= wu) ? __expf(sc[mt][hf][reg]) : 0.f;
                    pw[(mt * 16 + quad * 4 + reg) * 40 + hf * 16 + m16] = f2bf(p);
                }
            }
        }

        // ---- C-layout -> A-layout for P (per-wave buffer, lgkm wait only) ----
        __builtin_amdgcn_s_waitcnt(0xc07f);   // lgkmcnt(0), leave vmcnt alone
        bf16x8 pf0 = ldb8(pw + m16 * 40 + quad * 8);
        bf16x8 pf1 = ldb8(pw + (16 + m16) * 40 + quad * 8);

        // ---- O += P V; l += P 1 (V frags shared across m-tiles) ----
        #pragma unroll
        for (int dt = 0; dt < 8; dt++) {
            bf16x8 vf = ldb8(Vs + (dt * 16 + m16) * 32 + quad * 8);
            o[0][dt] = __builtin_amdgcn_mfma_f32_16x16x32_bf16(pf0, vf, o[0][dt], 0, 0, 0);
            o[1][dt] = __builtin_amdgcn_mfma_f32_16x16x32_bf16(pf1, vf, o[1][dt], 0, 0, 0);
        }
        lacc[0] = __builtin_amdgcn_mfma_f32_16x16x32_bf16(pf0, ones, lacc[0], 0, 0, 0);
        lacc[1] = __builtin_amdgcn_mfma_f32_16x16x32_bf16(pf1, ones, lacc[1], 0, 0, 0);
        __syncthreads();   // all LDS reads done before next stage overwrites
    }

    // ---- epilogue: y = O / l ----
    #pragma unroll
    for (int mt = 0; mt < 2; mt++) {
        float inv[4];
        #pragma unroll
        for (int reg = 0; reg < 4; reg++) inv[reg] = 1.0f / lacc[mt][reg];
        ushort* yb = Y + ((size_t)(b * T_ + tw + mt * 16 + quad * 4) * H_ + h) * D_ + m16;
        #pragma unroll
        for (int reg = 0; reg < 4; reg++)
            #pragma unroll
            for (int dt = 0; dt < 8; dt++)
                yb[(size_t)reg * H_ * D_ + dt * 16] = f2bf(o[mt][dt][reg] * inv[reg]);
    }
}

// ---------------------------------------------------------------------------
extern "C" void kernel_launch(void* const* d_in, const int* in_sizes, int n_in,
                              void* d_out, int out_size, void* d_ws, size_t ws_size,
                              hipStream_t stream) {
    const float* x     = (const float*)d_in[0];
    const float* ve    = (const float*)d_in[1];
    const float* cosb  = (const float*)d_in[2];
    const float* sinb  = (const float*)d_in[3];
    const float* Wq    = (const float*)d_in[4];
    const float* Wk    = (const float*)d_in[5];
    const float* Wv    = (const float*)d_in[6];
    const float* Wproj = (const float*)d_in[7];
    const float* Wg    = (const float*)d_in[8];
    const int*   wptr  = (const int*)d_in[9];
    float* out = (float*)d_out;

    // workspace layout (all bf16/ushort), ~63 MB
    ushort* xb    = (ushort*)d_ws;                    // M*C
    ushort* vbuf  = xb    + (size_t)M_ * C_;          // M*512
    ushort* Qp    = vbuf  + (size_t)M_ * 512;         // M*C (raw, permuted d)
    ushort* Kp    = Qp    + (size_t)M_ * C_;          // M*512 (permuted d)
    ushort* Vt    = Kp    + (size_t)M_ * 512;         // M*512
    ushort* yb16  = Vt    + (size_t)M_ * 512;         // M*C
    ushort* Wqkvb = yb16  + (size_t)M_ * C_;          // 2560*C (q/k rows dperm'd)
    ushort* Wpb   = Wqkvb + (size_t)NQKV_ * C_;       // C*C

    // fused cast of x + all weights (one launch; Wq/Wk rows permuted)
    cast_all<<<SEG4 / 256, 256, 0, stream>>>(x, Wq, Wk, Wv, Wproj, xb, Wqkvb, Wpb);

    // fused q|k|v projection, plain epilogue (q/k raw)
    gemm_qkv<<<dim3(NQKV_ / 128, M_ / 128), 256, 0, stream>>>(xb, Wqkvb, Qp, Kp, vbuf);

    // K: in-place rope + rms (Q handled inside attn)
    rope_rms_k<<<M_ * KV_ / 4, 256, 0, stream>>>(Kp, cosb, sinb);

    // ve-gate + transpose -> Vt
    gate_vt<<<dim3(T_ / 64, KV_, B_), 256, 0, stream>>>(vbuf, x, ve, Wg, Vt);

    // flash attention -> yb16
    attn_mfma<<<dim3(T_ / 128, H_, B_), 256, 0, stream>>>(Qp, Kp, Vt, yb16, wptr, cosb, sinb);

    // out = y @ Wproj^T (fp32 out)
    gemm_bf16_bt<false><<<dim3(C_ / 128, M_ / 128), 256, 0, stream>>>(yb16, Wpb, out, M_, C_, C_);
}

// Round 9
// 277.541 us; speedup vs baseline: 1.0514x; 1.0514x over previous
//
#include <hip/hip_runtime.h>
#include <hip/hip_bf16.h>
#include <math.h>

// Problem constants
#define B_  2
#define T_  2048
#define C_  1536
#define H_  12
#define KV_ 4
#define D_  128
#define M_  (B_*T_)   // 4096 rows
#define REP_ (H_/KV_) // 3
#define NQKV_ 2560    // fused q|k|v output width

typedef __bf16 bf16x8 __attribute__((ext_vector_type(8)));
typedef float  f32x4  __attribute__((ext_vector_type(4)));
typedef unsigned u32x4 __attribute__((ext_vector_type(4)));

union BCast { u32x4 u; bf16x8 b; ushort s[8]; };

__device__ inline bf16x8 ldb8(const ushort* p) {
    BCast c; c.u = *reinterpret_cast<const u32x4*>(p); return c.b;
}

__device__ inline ushort f2bf(float f) {
    union { float f; unsigned u; } v; v.f = f;
    unsigned u = v.u;
    return (ushort)((u + 0x7FFF + ((u >> 16) & 1)) >> 16);
}

__device__ inline float bf2f(ushort u) {
    union { unsigned u; float f; } v; v.u = (unsigned)u << 16;
    return v.f;
}

// async global->LDS, 16 bytes per lane; lds base must be wave-uniform
__device__ inline void async_copy16(const ushort* g, ushort* l) {
    __builtin_amdgcn_global_load_lds(
        (const __attribute__((address_space(1))) unsigned*)g,
        (__attribute__((address_space(3))) unsigned*)l, 16, 0, 0);
}

// ---------------------------------------------------------------------------
// bf16 MFMA GEMM (m97 structure): C[M,N] = A[M,K] * B[N,K]^T, M=4096 fixed.
// 1-D grid of 32*NBN blocks, XCD-aware swizzle: xcd=id&7 owns bm-stripe
// [xcd*4, xcd*4+4) and walks all bn -> per-XCD A working set 1.5 MB (L2-fits).
// ---------------------------------------------------------------------------
template<bool BF16OUT>
__global__ __launch_bounds__(256) void gemm_bf16_bt(const ushort* __restrict__ A,
                                                    const ushort* __restrict__ Bm,
                                                    void* __restrict__ Cp,
                                                    int N, int K) {
    const int id  = blockIdx.x;
    const int xcd = id & 7;
    const int c   = id >> 3;
    const int bm  = (xcd * 4 + (c & 3)) * 128;   // 32 bm-tiles total
    const int bn  = (c >> 2) * 128;

    __shared__ ushort As[128 * 32];
    __shared__ ushort Bs[128 * 32];
    const int tid  = threadIdx.x;
    const int wave = tid >> 6, lane = tid & 63;
    const int m16 = lane & 15, quad = lane >> 4;
    const int wm = (wave >> 1) * 64, wn = (wave & 1) * 64;

    const int lrow = lane >> 2;        // 0..15
    const int lcol = (lane & 3) * 8;   // 0,8,16,24
    const ushort* Ag = A  + (size_t)(bm + wave * 16 + lrow) * K + lcol;
    const ushort* Bg = Bm + (size_t)(bn + wave * 16 + lrow) * K + lcol;
    ushort* AsW0 = As + wave * 512;
    ushort* AsW1 = As + 2048 + wave * 512;
    ushort* BsW0 = Bs + wave * 512;
    ushort* BsW1 = Bs + 2048 + wave * 512;
    const size_t rowskip = (size_t)64 * K;

    f32x4 acc[4][4];
    #pragma unroll
    for (int i = 0; i < 4; i++)
        #pragma unroll
        for (int j = 0; j < 4; j++) acc[i][j] = (f32x4){0.f, 0.f, 0.f, 0.f};

    for (int k0 = 0; k0 < K; k0 += 32) {
        async_copy16(Ag + k0,           AsW0);
        async_copy16(Ag + k0 + rowskip, AsW1);
        async_copy16(Bg + k0,           BsW0);
        async_copy16(Bg + k0 + rowskip, BsW1);
        __syncthreads();

        bf16x8 af[4], bfr[4];
        #pragma unroll
        for (int i = 0; i < 4; i++)
            af[i] = ldb8(As + (wm + i * 16 + m16) * 32 + quad * 8);
        #pragma unroll
        for (int j = 0; j < 4; j++)
            bfr[j] = ldb8(Bs + (wn + j * 16 + m16) * 32 + quad * 8);
        #pragma unroll
        for (int i = 0; i < 4; i++)
            #pragma unroll
            for (int j = 0; j < 4; j++)
                acc[i][j] = __builtin_amdgcn_mfma_f32_16x16x32_bf16(af[i], bfr[j], acc[i][j], 0, 0, 0);
        __syncthreads();
    }

    #pragma unroll
    for (int i = 0; i < 4; i++) {
        #pragma unroll
        for (int reg = 0; reg < 4; reg++) {
            const int row = bm + wm + i * 16 + quad * 4 + reg;
            if constexpr (BF16OUT) {
                ushort* C = (ushort*)Cp;
                #pragma unroll
                for (int j = 0; j < 4; j++)
                    C[(size_t)row * N + bn + wn + j * 16 + m16] = f2bf(acc[i][j][reg]);
            } else {
                float* C = (float*)Cp;
                #pragma unroll
                for (int j = 0; j < 4; j++)
                    C[(size_t)row * N + bn + wn + j * 16 + m16] = acc[i][j][reg];
            }
        }
    }
}

// ---------------------------------------------------------------------------
// Fused segmented fp32->bf16 cast of x, Wq, Wk, Wv, Wproj (one launch).
// ---------------------------------------------------------------------------
#define SEG0 1572864   // x      : 4096*1536/4
#define SEG1 2162688   // + Wq   : 1536*1536/4
#define SEG2 2359296   // + Wk   : 512*1536/4
#define SEG3 2555904   // + Wv   : 512*1536/4
#define SEG4 3145728   // + Wproj: 1536*1536/4
__global__ __launch_bounds__(256) void cast_all(const float* __restrict__ x,
                                                const float* __restrict__ Wq,
                                                const float* __restrict__ Wk,
                                                const float* __restrict__ Wv,
                                                const float* __restrict__ Wp,
                                                ushort* __restrict__ xb,
                                                ushort* __restrict__ Wqkvb,
                                                ushort* __restrict__ Wpb) {
    const int i = blockIdx.x * 256 + threadIdx.x;
    const float* src; ushort* dst; int off;
    if (i < SEG0)      { src = x;  dst = xb;                          off = 0; }
    else if (i < SEG1) { src = Wq; dst = Wqkvb;                       off = SEG0; }
    else if (i < SEG2) { src = Wk; dst = Wqkvb + (size_t)1536 * C_;   off = SEG1; }
    else if (i < SEG3) { src = Wv; dst = Wqkvb + (size_t)2048 * C_;   off = SEG2; }
    else               { src = Wp; dst = Wpb;                         off = SEG3; }
    const int j = i - off;
    float4 v = ((const float4*)src)[j];
    ((ushort4*)dst)[j] = make_ushort4(f2bf(v.x), f2bf(v.y), f2bf(v.z), f2bf(v.w));
}

// ---------------------------------------------------------------------------
// Merged RoPE + RMSNorm for q AND k in one launch. Virtual head hx in [0,16):
// hx<12 -> q head hx (scale folds 1.2^2/sqrt(D)), hx>=12 -> k group hx-12.
// qkv col base = hx*128 for both (12*128 == 1536). 4 rows per 256-thr block.
// ---------------------------------------------------------------------------
__global__ __launch_bounds__(256) void rope_rms_qk(const ushort* __restrict__ qkv,
                                                   ushort* __restrict__ Qp,
                                                   ushort* __restrict__ Kp,
                                                   const float* __restrict__ cosb,
                                                   const float* __restrict__ sinb) {
    const int idx = blockIdx.x * 4 + (threadIdx.x >> 6);  // bt*16 + hx
    const int bt = idx >> 4;
    const int hx = idx & 15;
    const int b  = bt >> 11;          // T_ = 2048
    const int t  = bt & (T_ - 1);
    const ushort* p = qkv + (size_t)bt * NQKV_ + hx * D_;
    const int i = threadIdx.x & 63;
    const float x1 = bf2f(p[i]), x2 = bf2f(p[i + 64]);
    const float c = cosb[t * 64 + i], s = sinb[t * 64 + i];
    const float o1 =  x1 * c + x2 * s;
    const float o2 = -x1 * s + x2 * c;
    float ss = o1 * o1 + o2 * o2;
    #pragma unroll
    for (int off = 32; off > 0; off >>= 1) ss += __shfl_xor(ss, off);
    const bool isq = (hx < H_);
    const float osc = isq ? (1.2f * 1.2f * 0.08838834764831845f) : 1.0f;
    const float scale = rsqrtf(ss * (1.0f / 128.0f) + 1.1920928955078125e-07f) * osc;
    ushort* op = isq ? (Qp + ((size_t)(b * H_  + hx)      * T_ + t) * D_)
                     : (Kp + ((size_t)(b * KV_ + hx - H_) * T_ + t) * D_);
    op[i]      = f2bf(o1 * scale);
    op[i + 64] = f2bf(o2 * scale);
}

// ---------------------------------------------------------------------------
// Fused ve-gate + transpose: Vt[b][g][d][s] = qkv[bt][2048+g*128+d] + gate*ve
// ---------------------------------------------------------------------------
__global__ __launch_bounds__(256) void gate_vt(const ushort* __restrict__ qkv,
                                               const float* __restrict__ x,
                                               const float* __restrict__ ve,
                                               const float* __restrict__ Wg,
                                               ushort* __restrict__ Vt) {
    const int t0 = blockIdx.x * 64, g = blockIdx.y, b = blockIdx.z;
    __shared__ float gateS[64];
    __shared__ ushort tile[128][66];   // [d][t], padded
    const int tid = threadIdx.x;
    if (tid < 64) {
        const float* xr = x + (size_t)(b * T_ + t0 + tid) * C_;
        float acc = 0.f;
        #pragma unroll
        for (int c = 0; c < 12; c++) acc += xr[c] * Wg[g * 12 + c];
        gateS[tid] = 3.0f / (1.0f + __expf(-acc));
    }
    __syncthreads();
    #pragma unroll
    for (int i = 0; i < 32; i++) {
        int idx = i * 256 + tid;       // 0..8191
        int r = idx >> 7;              // t within tile
        int d = idx & 127;
        size_t offv = (size_t)(b * T_ + t0 + r) * NQKV_ + 2048 + g * D_ + d;
        size_t offe = (size_t)(b * T_ + t0 + r) * 512   + g * D_ + d;
        tile[d][r] = f2bf(bf2f(qkv[offv]) + gateS[r] * ve[offe]);
    }
    __syncthreads();
    ushort* ob = Vt + ((size_t)(b * KV_ + g) * D_) * T_ + t0;
    #pragma unroll
    for (int i = 0; i < 32; i++) {
        int idx = i * 256 + tid;
        int d = idx >> 6;              // 0..127
        int c = idx & 63;
        ob[(size_t)d * T_ + c] = tile[d][c];
    }
}

// ---------------------------------------------------------------------------
// Flash attention (R6 geometry): block = (b, h, 64 queries), 4 waves x 16 q.
// Static-max softmax + ones-MFMA l; K/V staged via global_load_lds.
// Ks [4 kc][32 s][32 d], Vs [128 d][32 s].
// ---------------------------------------------------------------------------
__global__ __launch_bounds__(256, 3) void attn_mfma(const ushort* __restrict__ Qp,
                                                    const ushort* __restrict__ Kp,
                                                    const ushort* __restrict__ Vt,
                                                    ushort* __restrict__ Y,
                                                    const int* __restrict__ wptr) {
    const int t0 = blockIdx.x * 64;
    const int h  = blockIdx.y, b = blockIdx.z;
    const int g  = h / REP_;
    const int tid  = threadIdx.x;
    const int wave = tid >> 6, lane = tid & 63;
    const int m16 = lane & 15, quad = lane >> 4;

    __shared__ ushort Ks[4 * 32 * 32];   // 8 KB
    __shared__ ushort Vs[128 * 32];      // 8 KB
    __shared__ ushort Pl[4][16 * 40];    // 5 KB, per-wave P buffers

    const int w = *wptr;
    const bool windowed = (w >= 0 && w < T_);
    const unsigned wu = windowed ? (unsigned)w : 0x7FFFFFFFu;
    int s_lo = 0;
    if (windowed) { s_lo = t0 - w; if (s_lo < 0) s_lo = 0; }
    const int s_hi = t0 + 63;
    const int ss0 = s_lo & ~31;
    const int tw = t0 + wave * 16;

    const ushort* qrow = Qp + ((size_t)(b * H_ + h) * T_ + tw + m16) * D_ + quad * 8;
    bf16x8 qa[4];
    #pragma unroll
    for (int kc = 0; kc < 4; kc++) qa[kc] = ldb8(qrow + kc * 32);

    const ushort* kbase = Kp + (size_t)(b * KV_ + g) * T_ * D_;
    const ushort* vbase = Vt + (size_t)(b * KV_ + g) * D_ * T_;

    const int c0 = wave, c1 = wave + 4;
    const ushort* kg0 = kbase + (size_t)((c0 & 1) * 16 + (lane >> 2)) * D_ + (c0 >> 1) * 32 + (lane & 3) * 8;
    const ushort* kg1 = kbase + (size_t)((c1 & 1) * 16 + (lane >> 2)) * D_ + (c1 >> 1) * 32 + (lane & 3) * 8;
    ushort* kl0 = Ks + c0 * 512;
    ushort* kl1 = Ks + c1 * 512;
    const ushort* vg0 = vbase + (size_t)(c0 * 16 + (lane >> 2)) * T_ + (lane & 3) * 8;
    const ushort* vg1 = vbase + (size_t)(c1 * 16 + (lane >> 2)) * T_ + (lane & 3) * 8;
    ushort* vl0 = Vs + c0 * 512;
    ushort* vl1 = Vs + c1 * 512;

    f32x4 o[8];
    #pragma unroll
    for (int dt = 0; dt < 8; dt++) o[dt] = (f32x4){0.f, 0.f, 0.f, 0.f};
    f32x4 lacc = (f32x4){0.f, 0.f, 0.f, 0.f};
    BCast onesc; onesc.u = (u32x4){0x3F803F80u, 0x3F803F80u, 0x3F803F80u, 0x3F803F80u};
    const bf16x8 ones = onesc.b;
    ushort* pw = &Pl[wave][0];

    for (int ss = ss0; ss <= s_hi; ss += 32) {
        const size_t koff = (size_t)ss * D_;
        async_copy16(kg0 + koff, kl0);
        async_copy16(kg1 + koff, kl1);
        async_copy16(vg0 + ss,   vl0);
        async_copy16(vg1 + ss,   vl1);
        __syncthreads();

        f32x4 s0 = (f32x4){0.f,0.f,0.f,0.f};
        f32x4 s1 = (f32x4){0.f,0.f,0.f,0.f};
        #pragma unroll
        for (int kc = 0; kc < 4; kc++) {
            bf16x8 kf0 = ldb8(Ks + kc * 1024 + m16 * 32 + quad * 8);
            bf16x8 kf1 = ldb8(Ks + kc * 1024 + (16 + m16) * 32 + quad * 8);
            s0 = __builtin_amdgcn_mfma_f32_16x16x32_bf16(qa[kc], kf0, s0, 0, 0, 0);
            s1 = __builtin_amdgcn_mfma_f32_16x16x32_bf16(qa[kc], kf1, s1, 0, 0, 0);
        }

        const int sA = ss + m16, sB = ss + 16 + m16;
        #pragma unroll
        for (int reg = 0; reg < 4; reg++) {
            const int t = tw + quad * 4 + reg;
            const float pa = ((unsigned)(t - sA) <= wu) ? __expf(s0[reg]) : 0.f;
            const float pb = ((unsigned)(t - sB) <= wu) ? __expf(s1[reg]) : 0.f;
            pw[(quad * 4 + reg) * 40 + m16]      = f2bf(pa);
            pw[(quad * 4 + reg) * 40 + 16 + m16] = f2bf(pb);
        }

        __builtin_amdgcn_s_waitcnt(0xc07f);   // lgkmcnt(0), leave vmcnt alone
        bf16x8 pfrag = ldb8(pw + m16 * 40 + quad * 8);

        #pragma unroll
        for (int dt = 0; dt < 8; dt++) {
            bf16x8 vf = ldb8(Vs + (dt * 16 + m16) * 32 + quad * 8);
            o[dt] = __builtin_amdgcn_mfma_f32_16x16x32_bf16(pfrag, vf, o[dt], 0, 0, 0);
        }
        lacc = __builtin_amdgcn_mfma_f32_16x16x32_bf16(pfrag, ones, lacc, 0, 0, 0);
        __syncthreads();
    }

    float inv[4];
    #pragma unroll
    for (int reg = 0; reg < 4; reg++) inv[reg] = 1.0f / lacc[reg];
    ushort* yb = Y + ((size_t)(b * T_ + tw + quad * 4) * H_ + h) * D_ + m16;
    #pragma unroll
    for (int reg = 0; reg < 4; reg++)
        #pragma unroll
        for (int dt = 0; dt < 8; dt++)
            yb[(size_t)reg * H_ * D_ + dt * 16] = f2bf(o[dt][reg] * inv[reg]);
}

// ---------------------------------------------------------------------------
extern "C" void kernel_launch(void* const* d_in, const int* in_sizes, int n_in,
                              void* d_out, int out_size, void* d_ws, size_t ws_size,
                              hipStream_t stream) {
    const float* x     = (const float*)d_in[0];
    const float* ve    = (const float*)d_in[1];
    const float* cosb  = (const float*)d_in[2];
    const float* sinb  = (const float*)d_in[3];
    const float* Wq    = (const float*)d_in[4];
    const float* Wk    = (const float*)d_in[5];
    const float* Wv    = (const float*)d_in[6];
    const float* Wproj = (const float*)d_in[7];
    const float* Wg    = (const float*)d_in[8];
    const int*   wptr  = (const int*)d_in[9];
    float* out = (float*)d_out;

    // workspace layout (all bf16/ushort), ~67 MB
    ushort* xb    = (ushort*)d_ws;                    // M*C
    ushort* qkv   = xb    + (size_t)M_ * C_;          // M*2560 (later aliased: yb16)
    ushort* Qp    = qkv   + (size_t)M_ * NQKV_;       // M*C
    ushort* Kp    = Qp    + (size_t)M_ * C_;          // M*512
    ushort* Vt    = Kp    + (size_t)M_ * 512;         // M*512
    ushort* Wqkvb = Vt    + (size_t)M_ * 512;         // 2560*C
    ushort* Wpb   = Wqkvb + (size_t)NQKV_ * C_;       // C*C

    // fused cast of x + all weights (one launch)
    cast_all<<<SEG4 / 256, 256, 0, stream>>>(x, Wq, Wk, Wv, Wproj, xb, Wqkvb, Wpb);

    // fused q|k|v projection (XCD-swizzled 1-D grid: 32 bm x 20 bn)
    gemm_bf16_bt<true><<<32 * (NQKV_ / 128), 256, 0, stream>>>(xb, Wqkvb, qkv, NQKV_, C_);

    // ve-gate + transpose -> Vt
    gate_vt<<<dim3(T_ / 64, KV_, B_), 256, 0, stream>>>(qkv, x, ve, Wg, Vt);

    // merged rope + rmsnorm for q and k (one launch, 16 virtual heads)
    rope_rms_qk<<<M_ * 16 / 4, 256, 0, stream>>>(qkv, Qp, Kp, cosb, sinb);

    // flash attention -> yb16 (aliases qkv space — qkv consumed above)
    ushort* yb16 = qkv;
    attn_mfma<<<dim3(T_ / 64, H_, B_), 256, 0, stream>>>(Qp, Kp, Vt, yb16, wptr);

    // out = y @ Wproj^T (fp32 out, XCD-swizzled 1-D grid: 32 bm x 12 bn)
    gemm_bf16_bt<false><<<32 * (C_ / 128), 256, 0, stream>>>(yb16, Wpb, out, C_, C_);
}